// Round 4
// baseline (268.738 us; speedup 1.0000x reference)
//
#include <hip/hip_runtime.h>

#define B_ 2
#define N_ 2048
#define H_ 8
#define DH_ 32
#define E_ 65536
#define DIN_ 256
#define KT 256
#define PAD 4
#define ECAP 32
#define LOG2E 1.4426950408889634f
#define QSCALE 0.2550349880f          /* log2(e)/sqrt(32) */
#define LOGMIN2 -19.931568569324174f  /* log2(1e-6) */

typedef short bf16x8 __attribute__((ext_vector_type(8)));
typedef float floatx4 __attribute__((ext_vector_type(4)));

__device__ __forceinline__ unsigned short f2b(float f){
  union { float f; unsigned int u; } v; v.f = f;
  return (unsigned short)((v.u + 0x7fffu + ((v.u >> 16) & 1u)) >> 16);
}
__device__ __forceinline__ bf16x8 f8_to_bf(const float* p){
  float4 a = *(const float4*)p, b = *(const float4*)(p + 4);
  bf16x8 r;
  r[0] = (short)f2b(a.x); r[1] = (short)f2b(a.y); r[2] = (short)f2b(a.z); r[3] = (short)f2b(a.w);
  r[4] = (short)f2b(b.x); r[5] = (short)f2b(b.y); r[6] = (short)f2b(b.z); r[7] = (short)f2b(b.w);
  return r;
}
__device__ __forceinline__ unsigned int fbits(float f){
  union { float f; unsigned int u; } v; v.f = f; return v.u;
}
__device__ __forceinline__ float ftrunc16(float f){
  union { unsigned int u; float f; } v; v.u = fbits(f) & 0xffff0000u; return v.f;
}
// pack hi16(lo), hi16(hi) -> one dword (bf16 truncation), single v_perm
__device__ __forceinline__ unsigned int pack_trunc(float lo, float hi){
  return __builtin_amdgcn_perm(fbits(hi), fbits(lo), 0x07060302u);
}

// ---------------- prep: ffn (blocks 0..511) + fill (512..1023) + wT (1024..1279) ----------------
__global__ __launch_bounds__(256) void prep_kernel(
    const float* __restrict__ eattr,
    const float* __restrict__ w1, const float* __restrict__ b1,
    const float* __restrict__ w2, const float* __restrict__ b2,
    float* __restrict__ ea,
    const int* __restrict__ ei, int* __restrict__ cnt, unsigned int* __restrict__ pck,
    const float* __restrict__ w, unsigned short* __restrict__ wT)
{
  int bb = blockIdx.x, tid = threadIdx.x;
  if (bb < 512){
    __shared__ float W1[64], W2[64], Bv1[8], Bv2[8];
    if (tid < 64){ W1[tid] = w1[tid]; W2[tid] = w2[tid]; }
    if (tid < 8){ Bv1[tid] = b1[tid]; Bv2[tid] = b2[tid]; }
    __syncthreads();
    int gid = bb * 256 + tid;                 // b*E + e
    const float* ep = eattr + (size_t)gid * 8;
    float cur[8];
#pragma unroll
    for (int i = 0; i < 8; ++i) cur[i] = ep[i];
#pragma unroll
    for (int pass = 0; pass < 2; ++pass){
      float t[8];
#pragma unroll
      for (int j = 0; j < 8; ++j){
        float s = Bv1[j];
#pragma unroll
        for (int i = 0; i < 8; ++i) s += cur[i] * W1[i * 8 + j];
        t[j] = fmaxf(s, 0.f);
      }
#pragma unroll
      for (int j = 0; j < 8; ++j){
        float s = Bv2[j];
#pragma unroll
        for (int i = 0; i < 8; ++i) s += t[i] * W2[i * 8 + j];
        cur[j] = s;
      }
    }
    float* op = ea + (size_t)gid * 8;
#pragma unroll
    for (int j = 0; j < 8; ++j) op[j] = cur[j] * LOG2E;   // pre-scale for base-2 softmax
  } else if (bb < 1024){
    int gid = (bb - 512) * 256 + tid;         // 0..131071
    int b = gid >> 16, e = gid & (E_ - 1);
    int u = ei[(size_t)b * 2 * E_ + e];
    int v = ei[(size_t)b * 2 * E_ + E_ + e];
    int bucket = ((b << 11) + u) * 8 + (v >> 8);
    int slot = atomicAdd(&cnt[bucket], 1);
    if (slot < ECAP) pck[(size_t)bucket * ECAP + slot] = ((unsigned int)e << 11) | (unsigned int)v;
  } else {
    int k = bb - 1024;                        // 0..255
    for (int c = tid; c < 768; c += 256)
      wT[(size_t)c * 256 + k] = f2b(w[(size_t)k * 768 + c]);
  }
}

// ---------------- QKV projection; Q pre-scaled by log2e/sqrt(DH) ----------------
__global__ __launch_bounds__(256) void qkv_kernel(
    const float* __restrict__ x, const unsigned short* __restrict__ wT,
    const float* __restrict__ bias,
    unsigned short* __restrict__ Qb, unsigned short* __restrict__ Kb, unsigned short* __restrict__ Vt)
{
  int tid = threadIdx.x;
  int wave = tid >> 6, lane = tid & 63, m = lane & 15, quad = lane >> 4;
  int rowbase = blockIdx.x * 16;
  int colbase = blockIdx.y * 64 + wave * 16;
  floatx4 acc = {0.f, 0.f, 0.f, 0.f};
#pragma unroll
  for (int kb = 0; kb < 8; ++kb){
    bf16x8 af = f8_to_bf(x + (size_t)(rowbase + m) * DIN_ + kb * 32 + quad * 8);
    bf16x8 bf = *(const bf16x8*)(wT + (size_t)(colbase + m) * DIN_ + kb * 32 + quad * 8);
    acc = __builtin_amdgcn_mfma_f32_16x16x32_bf16(af, bf, acc, 0, 0, 0);
  }
  int ccol = colbase + m;
  int which = ccol >> 8, hh = (ccol >> 5) & 7, dh = ccol & 31;
  float bv = bias[ccol];
#pragma unroll
  for (int r = 0; r < 4; ++r){
    int row = rowbase + quad * 4 + r;
    int bidx = row >> 11, n = row & (N_ - 1);
    float val = acc[r] + bv;
    size_t bh = (size_t)(bidx * H_ + hh);
    if (which == 0)      Qb[(bh * N_ + n) * DH_ + dh] = f2b(val * QSCALE);
    else if (which == 1) Kb[(bh * N_ + n) * DH_ + dh] = f2b(val);
    else                 Vt[(bh * DH_ + dh) * N_ + n] = f2b(val);
  }
}

// ---------------- fused single-pass flash attention: 1 WG = (b, h, 32 q-rows) ----------------
__global__ __launch_bounds__(256) void attn_kernel(
    const unsigned short* __restrict__ Qb, const unsigned short* __restrict__ Kb,
    const unsigned short* __restrict__ Vt, const float* __restrict__ adj,
    const float* __restrict__ ea, const int* __restrict__ cnt, const unsigned int* __restrict__ pck,
    const float* __restrict__ shifts, const float* __restrict__ widths,
    const float* __restrict__ selfW, float* __restrict__ out)
{
  __shared__ float S[32][KT + PAD];      // 32.5 KB; reused as O-reduction scratch at end
  __shared__ float mpart[4][32];
  __shared__ float mrowW[4][32];
  __shared__ float arowW[4][32];
  __shared__ float lfin[4][32];

  int bid = blockIdx.x;
  int qt = bid & 63, h = (bid >> 6) & 7, b = bid >> 9;
  int qbase = qt * 32;
  int tid = threadIdx.x, wave = tid >> 6, lane = tid & 63, m = lane & 15, quad = lane >> 4;
  float shift_h = shifts[h];
  float w_h = widths[h];
  float ni = -LOG2E / (2.f * w_h * w_h);         // negative, includes log2e
  float selfW_h = selfW[h] * LOG2E;
  size_t krow = (size_t)(b * H_ + h) * N_;
  size_t vrow = (size_t)(b * H_ + h) * DH_;
  bf16x8 qfrag0 = *(const bf16x8*)(Qb + (krow + qbase + m) * DH_ + quad * 8);
  bf16x8 qfrag1 = *(const bf16x8*)(Qb + (krow + qbase + 16 + m) * DH_ + quad * 8);

  float mcurA = -1e30f, mcurB = -1e30f;   // running row max (lane<32 keyed by row; reg copy per lane)
  float lcurA = 0.f, lcurB = 0.f;         // this wave's sum-exp partials, rows m / 16+m
  floatx4 oA0 = {0,0,0,0}, oA1 = {0,0,0,0}, oB0 = {0,0,0,0}, oB1 = {0,0,0,0};

  int c0 = wave * 64 + quad * 8;
  int dqk = 0;

  for (int kt = 0; kt < N_ / KT; ++kt){
    int k0 = kt * KT;
    bool diagtile = (k0 == (qbase & ~(KT - 1)));
    dqk = qbase - k0;
    // ---- QK^T MFMA for both row groups (+ self-loop on diagonal tile) ----
#pragma unroll
    for (int s = 0; s < 4; ++s){
      int colofs = wave * 64 + s * 16;
      bf16x8 kf = *(const bf16x8*)(Kb + (krow + k0 + colofs + m) * DH_ + quad * 8);
      floatx4 aA = {0,0,0,0}, aB = {0,0,0,0};
      aA = __builtin_amdgcn_mfma_f32_16x16x32_bf16(qfrag0, kf, aA, 0, 0, 0);
      aB = __builtin_amdgcn_mfma_f32_16x16x32_bf16(qfrag1, kf, aB, 0, 0, 0);
      int t = colofs + m - dqk;
#pragma unroll
      for (int r = 0; r < 4; ++r){
        float vA = aA[r], vB = aB[r];
        if (diagtile && t == quad * 4 + r)      vA += selfW_h;
        if (diagtile && t == 16 + quad * 4 + r) vB += selfW_h;
        S[quad * 4 + r][colofs + m] = vA;
        S[16 + quad * 4 + r][colofs + m] = vB;
      }
    }
    __syncthreads();
    // ---- + edge scatter (unique (u,v) per batch -> race-free) ----
#pragma unroll
    for (int ii = 0; ii < 4; ++ii){
      int i = tid + ii * 256;
      int r = i >> 5, slot = i & (ECAP - 1);
      int bucket = (b * N_ + qbase + r) * 8 + kt;
      int nb = cnt[bucket]; nb = nb > ECAP ? ECAP : nb;
      if (slot < nb){
        unsigned int p = pck[(size_t)bucket * ECAP + slot];
        int vv = (int)(p & (N_ - 1));
        int e  = (int)(p >> 11);
        S[r][vv - k0] += ea[((size_t)b * E_ + e) * H_ + h];
      }
    }
    __syncthreads();
    // ---- read S frags to regs, add moire in-reg, per-row tile max ----
    const float* SrA = &S[m][c0];
    const float* SrB = &S[16 + m][c0];
    const float* ArA = adj + ((size_t)b * N_ + qbase + m) * N_ + k0 + c0;
    const float* ArB = adj + ((size_t)b * N_ + qbase + 16 + m) * N_ + k0 + c0;
    float4 sA0 = *(const float4*)(SrA),      sA1 = *(const float4*)(SrA + 4);
    float4 sA2 = *(const float4*)(SrA + 32), sA3 = *(const float4*)(SrA + 36);
    float4 sB0 = *(const float4*)(SrB),      sB1 = *(const float4*)(SrB + 4);
    float4 sB2 = *(const float4*)(SrB + 32), sB3 = *(const float4*)(SrB + 36);
    {
      float4 a0 = *(const float4*)(ArA),      a1 = *(const float4*)(ArA + 4);
      float4 a2 = *(const float4*)(ArA + 32), a3 = *(const float4*)(ArA + 36);
      float d;
      d = a0.x - shift_h; sA0.x += fmaxf(d * d * ni, LOGMIN2);
      d = a0.y - shift_h; sA0.y += fmaxf(d * d * ni, LOGMIN2);
      d = a0.z - shift_h; sA0.z += fmaxf(d * d * ni, LOGMIN2);
      d = a0.w - shift_h; sA0.w += fmaxf(d * d * ni, LOGMIN2);
      d = a1.x - shift_h; sA1.x += fmaxf(d * d * ni, LOGMIN2);
      d = a1.y - shift_h; sA1.y += fmaxf(d * d * ni, LOGMIN2);
      d = a1.z - shift_h; sA1.z += fmaxf(d * d * ni, LOGMIN2);
      d = a1.w - shift_h; sA1.w += fmaxf(d * d * ni, LOGMIN2);
      d = a2.x - shift_h; sA2.x += fmaxf(d * d * ni, LOGMIN2);
      d = a2.y - shift_h; sA2.y += fmaxf(d * d * ni, LOGMIN2);
      d = a2.z - shift_h; sA2.z += fmaxf(d * d * ni, LOGMIN2);
      d = a2.w - shift_h; sA2.w += fmaxf(d * d * ni, LOGMIN2);
      d = a3.x - shift_h; sA3.x += fmaxf(d * d * ni, LOGMIN2);
      d = a3.y - shift_h; sA3.y += fmaxf(d * d * ni, LOGMIN2);
      d = a3.z - shift_h; sA3.z += fmaxf(d * d * ni, LOGMIN2);
      d = a3.w - shift_h; sA3.w += fmaxf(d * d * ni, LOGMIN2);
      a0 = *(const float4*)(ArB);      a1 = *(const float4*)(ArB + 4);
      a2 = *(const float4*)(ArB + 32); a3 = *(const float4*)(ArB + 36);
      d = a0.x - shift_h; sB0.x += fmaxf(d * d * ni, LOGMIN2);
      d = a0.y - shift_h; sB0.y += fmaxf(d * d * ni, LOGMIN2);
      d = a0.z - shift_h; sB0.z += fmaxf(d * d * ni, LOGMIN2);
      d = a0.w - shift_h; sB0.w += fmaxf(d * d * ni, LOGMIN2);
      d = a1.x - shift_h; sB1.x += fmaxf(d * d * ni, LOGMIN2);
      d = a1.y - shift_h; sB1.y += fmaxf(d * d * ni, LOGMIN2);
      d = a1.z - shift_h; sB1.z += fmaxf(d * d * ni, LOGMIN2);
      d = a1.w - shift_h; sB1.w += fmaxf(d * d * ni, LOGMIN2);
      d = a2.x - shift_h; sB2.x += fmaxf(d * d * ni, LOGMIN2);
      d = a2.y - shift_h; sB2.y += fmaxf(d * d * ni, LOGMIN2);
      d = a2.z - shift_h; sB2.z += fmaxf(d * d * ni, LOGMIN2);
      d = a2.w - shift_h; sB2.w += fmaxf(d * d * ni, LOGMIN2);
      d = a3.x - shift_h; sB3.x += fmaxf(d * d * ni, LOGMIN2);
      d = a3.y - shift_h; sB3.y += fmaxf(d * d * ni, LOGMIN2);
      d = a3.z - shift_h; sB3.z += fmaxf(d * d * ni, LOGMIN2);
      d = a3.w - shift_h; sB3.w += fmaxf(d * d * ni, LOGMIN2);
    }
    float lmA = fmaxf(fmaxf(fmaxf(sA0.x, sA0.y), fmaxf(sA0.z, sA0.w)),
                      fmaxf(fmaxf(sA1.x, sA1.y), fmaxf(sA1.z, sA1.w)));
    lmA = fmaxf(lmA, fmaxf(fmaxf(fmaxf(sA2.x, sA2.y), fmaxf(sA2.z, sA2.w)),
                           fmaxf(fmaxf(sA3.x, sA3.y), fmaxf(sA3.z, sA3.w))));
    float lmB = fmaxf(fmaxf(fmaxf(sB0.x, sB0.y), fmaxf(sB0.z, sB0.w)),
                      fmaxf(fmaxf(sB1.x, sB1.y), fmaxf(sB1.z, sB1.w)));
    lmB = fmaxf(lmB, fmaxf(fmaxf(fmaxf(sB2.x, sB2.y), fmaxf(sB2.z, sB2.w)),
                           fmaxf(fmaxf(sB3.x, sB3.y), fmaxf(sB3.z, sB3.w))));
    lmA = fmaxf(lmA, __shfl_xor(lmA, 16)); lmA = fmaxf(lmA, __shfl_xor(lmA, 32));
    lmB = fmaxf(lmB, __shfl_xor(lmB, 16)); lmB = fmaxf(lmB, __shfl_xor(lmB, 32));
    if (quad == 0){ mpart[wave][m] = lmA; mpart[wave][16 + m] = lmB; }
    __syncthreads();
    // ---- per-wave redundant m/alpha update (identical across waves) ----
    if (lane < 32){
      float mcur = (lane < 16) ? mcurA : mcurB;
      float tmax = fmaxf(fmaxf(mpart[0][lane], mpart[1][lane]),
                         fmaxf(mpart[2][lane], mpart[3][lane]));
      float mnew = fmaxf(mcur, tmax);
      mrowW[wave][lane] = mnew;
      arowW[wave][lane] = exp2f(mcur - mnew);
      if (lane < 16) mcurA = mnew; else mcurB = mnew;
    }
    __threadfence_block();
    // broadcast mcur reg copies to all quads (keep lanes consistent)
    mcurA = mrowW[wave][m];
    mcurB = mrowW[wave][16 + m];
    float mrA = mcurA, mrB = mcurB;
    float alA = arowW[wave][m], alB = arowW[wave][16 + m];
    float4 aqA = *(const float4*)&arowW[wave][quad * 4];
    float4 aqB = *(const float4*)&arowW[wave][16 + quad * 4];
    oA0[0] *= aqA.x; oA0[1] *= aqA.y; oA0[2] *= aqA.z; oA0[3] *= aqA.w;
    oA1[0] *= aqA.x; oA1[1] *= aqA.y; oA1[2] *= aqA.z; oA1[3] *= aqA.w;
    oB0[0] *= aqB.x; oB0[1] *= aqB.y; oB0[2] *= aqB.z; oB0[3] *= aqB.w;
    oB1[0] *= aqB.x; oB1[1] *= aqB.y; oB1[2] *= aqB.z; oB1[3] *= aqB.w;
    // ---- P = exp2(S - m), truncate->bf16 pack, PV MFMA ----
    bf16x8 vf00 = *(const bf16x8*)(Vt + (vrow + m) * N_      + k0 + c0);
    bf16x8 vf01 = *(const bf16x8*)(Vt + (vrow + 16 + m) * N_ + k0 + c0);
    bf16x8 vf10 = *(const bf16x8*)(Vt + (vrow + m) * N_      + k0 + c0 + 32);
    bf16x8 vf11 = *(const bf16x8*)(Vt + (vrow + 16 + m) * N_ + k0 + c0 + 32);
    float psA = 0.f, psB = 0.f;
    union { bf16x8 v; unsigned int u[4]; } pf;
    float p0, p1;
    // group A chunk 0
    p0 = exp2f(sA0.x - mrA); p1 = exp2f(sA0.y - mrA); psA += ftrunc16(p0) + ftrunc16(p1); pf.u[0] = pack_trunc(p0, p1);
    p0 = exp2f(sA0.z - mrA); p1 = exp2f(sA0.w - mrA); psA += ftrunc16(p0) + ftrunc16(p1); pf.u[1] = pack_trunc(p0, p1);
    p0 = exp2f(sA1.x - mrA); p1 = exp2f(sA1.y - mrA); psA += ftrunc16(p0) + ftrunc16(p1); pf.u[2] = pack_trunc(p0, p1);
    p0 = exp2f(sA1.z - mrA); p1 = exp2f(sA1.w - mrA); psA += ftrunc16(p0) + ftrunc16(p1); pf.u[3] = pack_trunc(p0, p1);
    oA0 = __builtin_amdgcn_mfma_f32_16x16x32_bf16(pf.v, vf00, oA0, 0, 0, 0);
    oA1 = __builtin_amdgcn_mfma_f32_16x16x32_bf16(pf.v, vf01, oA1, 0, 0, 0);
    // group A chunk 1
    p0 = exp2f(sA2.x - mrA); p1 = exp2f(sA2.y - mrA); psA += ftrunc16(p0) + ftrunc16(p1); pf.u[0] = pack_trunc(p0, p1);
    p0 = exp2f(sA2.z - mrA); p1 = exp2f(sA2.w - mrA); psA += ftrunc16(p0) + ftrunc16(p1); pf.u[1] = pack_trunc(p0, p1);
    p0 = exp2f(sA3.x - mrA); p1 = exp2f(sA3.y - mrA); psA += ftrunc16(p0) + ftrunc16(p1); pf.u[2] = pack_trunc(p0, p1);
    p0 = exp2f(sA3.z - mrA); p1 = exp2f(sA3.w - mrA); psA += ftrunc16(p0) + ftrunc16(p1); pf.u[3] = pack_trunc(p0, p1);
    oA0 = __builtin_amdgcn_mfma_f32_16x16x32_bf16(pf.v, vf10, oA0, 0, 0, 0);
    oA1 = __builtin_amdgcn_mfma_f32_16x16x32_bf16(pf.v, vf11, oA1, 0, 0, 0);
    // group B chunk 0
    p0 = exp2f(sB0.x - mrB); p1 = exp2f(sB0.y - mrB); psB += ftrunc16(p0) + ftrunc16(p1); pf.u[0] = pack_trunc(p0, p1);
    p0 = exp2f(sB0.z - mrB); p1 = exp2f(sB0.w - mrB); psB += ftrunc16(p0) + ftrunc16(p1); pf.u[1] = pack_trunc(p0, p1);
    p0 = exp2f(sB1.x - mrB); p1 = exp2f(sB1.y - mrB); psB += ftrunc16(p0) + ftrunc16(p1); pf.u[2] = pack_trunc(p0, p1);
    p0 = exp2f(sB1.z - mrB); p1 = exp2f(sB1.w - mrB); psB += ftrunc16(p0) + ftrunc16(p1); pf.u[3] = pack_trunc(p0, p1);
    oB0 = __builtin_amdgcn_mfma_f32_16x16x32_bf16(pf.v, vf00, oB0, 0, 0, 0);
    oB1 = __builtin_amdgcn_mfma_f32_16x16x32_bf16(pf.v, vf01, oB1, 0, 0, 0);
    // group B chunk 1
    p0 = exp2f(sB2.x - mrB); p1 = exp2f(sB2.y - mrB); psB += ftrunc16(p0) + ftrunc16(p1); pf.u[0] = pack_trunc(p0, p1);
    p0 = exp2f(sB2.z - mrB); p1 = exp2f(sB2.w - mrB); psB += ftrunc16(p0) + ftrunc16(p1); pf.u[1] = pack_trunc(p0, p1);
    p0 = exp2f(sB3.x - mrB); p1 = exp2f(sB3.y - mrB); psB += ftrunc16(p0) + ftrunc16(p1); pf.u[2] = pack_trunc(p0, p1);
    p0 = exp2f(sB3.z - mrB); p1 = exp2f(sB3.w - mrB); psB += ftrunc16(p0) + ftrunc16(p1); pf.u[3] = pack_trunc(p0, p1);
    oB0 = __builtin_amdgcn_mfma_f32_16x16x32_bf16(pf.v, vf10, oB0, 0, 0, 0);
    oB1 = __builtin_amdgcn_mfma_f32_16x16x32_bf16(pf.v, vf11, oB1, 0, 0, 0);
    psA += __shfl_xor(psA, 16); psA += __shfl_xor(psA, 32);
    psB += __shfl_xor(psB, 16); psB += __shfl_xor(psB, 32);
    lcurA = lcurA * alA + psA;
    lcurB = lcurB * alB + psB;
  }

  // ---- cross-wave O + l reduction (reuse S as scratch), output fp32 ----
  float* Op = &S[0][0];     // [wave*32 + row][32] flat
#pragma unroll
  for (int r = 0; r < 4; ++r){
    Op[(wave * 32 + quad * 4 + r) * 32 + m]           = oA0[r];
    Op[(wave * 32 + quad * 4 + r) * 32 + 16 + m]      = oA1[r];
    Op[(wave * 32 + 16 + quad * 4 + r) * 32 + m]      = oB0[r];
    Op[(wave * 32 + 16 + quad * 4 + r) * 32 + 16 + m] = oB1[r];
  }
  if (lane < 16){ lfin[wave][m] = lcurA; lfin[wave][16 + m] = lcurB; }
  __syncthreads();
#pragma unroll
  for (int ii = 0; ii < 4; ++ii){
    int i = tid + ii * 256;
    int r = i >> 5, d = i & 31;
    float o = Op[r * 32 + d] + Op[(32 + r) * 32 + d] + Op[(64 + r) * 32 + d] + Op[(96 + r) * 32 + d];
    float l = lfin[0][r] + lfin[1][r] + lfin[2][r] + lfin[3][r];
    out[((size_t)b * N_ + qbase + r) * (H_ * DH_) + h * DH_ + d] = o / l;
  }
}

extern "C" void kernel_launch(void* const* d_in, const int* in_sizes, int n_in,
                              void* d_out, int out_size, void* d_ws, size_t ws_size,
                              hipStream_t stream)
{
  const float* x      = (const float*)d_in[0];
  const float* adj    = (const float*)d_in[1];
  const float* eattr  = (const float*)d_in[2];
  const float* qkvw   = (const float*)d_in[3];
  const float* qkvb   = (const float*)d_in[4];
  const float* ew1    = (const float*)d_in[5];
  const float* eb1    = (const float*)d_in[6];
  const float* ew2    = (const float*)d_in[7];
  const float* eb2    = (const float*)d_in[8];
  const float* shifts = (const float*)d_in[9];
  const float* widths = (const float*)d_in[10];
  const float* selfW  = (const float*)d_in[11];
  const int*   ei     = (const int*)d_in[12];
  float* out = (float*)d_out;

  char* ws = (char*)d_ws;
  unsigned short* Qb  = (unsigned short*)(ws);                        // 2 MB
  unsigned short* Kb  = (unsigned short*)(ws + ((size_t)2 << 20));    // 2 MB
  unsigned short* Vt  = (unsigned short*)(ws + ((size_t)4 << 20));    // 2 MB
  unsigned short* wT  = (unsigned short*)(ws + ((size_t)6 << 20));    // 384 KB
  float*          ea  = (float*)(ws + ((size_t)7 << 20));             // 4 MB
  int*            cnt = (int*)(ws + ((size_t)11 << 20));              // 128 KB
  unsigned int*  pck  = (unsigned int*)(ws + ((size_t)12 << 20));     // 4 MB (total 16 MB)

  hipMemsetAsync(cnt, 0, (size_t)B_ * N_ * 8 * sizeof(int), stream);
  hipLaunchKernelGGL(prep_kernel, dim3(1280), dim3(256), 0, stream,
                     eattr, ew1, eb1, ew2, eb2, ea, ei, cnt, pck, qkvw, wT);
  hipLaunchKernelGGL(qkv_kernel, dim3(256, 12), dim3(256), 0, stream, x, wT, qkvb, Qb, Kb, Vt);
  hipLaunchKernelGGL(attn_kernel, dim3(B_ * H_ * (N_ / 32)), dim3(256), 0, stream,
                     Qb, Kb, Vt, adj, ea, cnt, pck, shifts, widths, selfW, out);
}

// Round 6
// 266.422 us; speedup vs baseline: 1.0087x; 1.0087x over previous
//
#include <hip/hip_runtime.h>

#define B_ 2
#define N_ 2048
#define H_ 8
#define DH_ 32
#define E_ 65536
#define DIN_ 256
#define KT 256
#define PAD 4
#define ECAP 32
#define LOG2E 1.4426950408889634f
#define QSCALE 0.2550349880f          /* log2(e)/sqrt(32) */
#define LOGMIN2 -19.931568569324174f  /* log2(1e-6) */

typedef short bf16x8 __attribute__((ext_vector_type(8)));
typedef float floatx4 __attribute__((ext_vector_type(4)));

__device__ __forceinline__ unsigned short f2b(float f){
  union { float f; unsigned int u; } v; v.f = f;
  return (unsigned short)((v.u + 0x7fffu + ((v.u >> 16) & 1u)) >> 16);
}
__device__ __forceinline__ bf16x8 f8_to_bf(const float* p){
  float4 a = *(const float4*)p, b = *(const float4*)(p + 4);
  bf16x8 r;
  r[0] = (short)f2b(a.x); r[1] = (short)f2b(a.y); r[2] = (short)f2b(a.z); r[3] = (short)f2b(a.w);
  r[4] = (short)f2b(b.x); r[5] = (short)f2b(b.y); r[6] = (short)f2b(b.z); r[7] = (short)f2b(b.w);
  return r;
}
__device__ __forceinline__ unsigned int fbits(float f){
  union { float f; unsigned int u; } v; v.f = f; return v.u;
}
__device__ __forceinline__ float ftrunc16(float f){
  union { unsigned int u; float f; } v; v.u = fbits(f) & 0xffff0000u; return v.f;
}
// pack hi16(lo), hi16(hi) -> one dword (bf16 truncation), single v_perm
__device__ __forceinline__ unsigned int pack_trunc(float lo, float hi){
  return __builtin_amdgcn_perm(fbits(hi), fbits(lo), 0x07060302u);
}

// ---------------- prep: ffn (blocks 0..511) + fill (512..1023) + wT (1024..1279) ----------------
__global__ __launch_bounds__(256) void prep_kernel(
    const float* __restrict__ eattr,
    const float* __restrict__ w1, const float* __restrict__ b1,
    const float* __restrict__ w2, const float* __restrict__ b2,
    float* __restrict__ ea,
    const int* __restrict__ ei, int* __restrict__ cnt, unsigned int* __restrict__ pck,
    const float* __restrict__ w, unsigned short* __restrict__ wT)
{
  int bb = blockIdx.x, tid = threadIdx.x;
  if (bb < 512){
    __shared__ float W1[64], W2[64], Bv1[8], Bv2[8];
    if (tid < 64){ W1[tid] = w1[tid]; W2[tid] = w2[tid]; }
    if (tid < 8){ Bv1[tid] = b1[tid]; Bv2[tid] = b2[tid]; }
    __syncthreads();
    int gid = bb * 256 + tid;                 // b*E + e
    const float* ep = eattr + (size_t)gid * 8;
    float cur[8];
#pragma unroll
    for (int i = 0; i < 8; ++i) cur[i] = ep[i];
#pragma unroll
    for (int pass = 0; pass < 2; ++pass){
      float t[8];
#pragma unroll
      for (int j = 0; j < 8; ++j){
        float s = Bv1[j];
#pragma unroll
        for (int i = 0; i < 8; ++i) s += cur[i] * W1[i * 8 + j];
        t[j] = fmaxf(s, 0.f);
      }
#pragma unroll
      for (int j = 0; j < 8; ++j){
        float s = Bv2[j];
#pragma unroll
        for (int i = 0; i < 8; ++i) s += t[i] * W2[i * 8 + j];
        cur[j] = s;
      }
    }
    float* op = ea + (size_t)gid * 8;
#pragma unroll
    for (int j = 0; j < 8; ++j) op[j] = cur[j] * LOG2E;   // pre-scale for base-2 softmax
  } else if (bb < 1024){
    int gid = (bb - 512) * 256 + tid;         // 0..131071
    int b = gid >> 16, e = gid & (E_ - 1);
    int u = ei[(size_t)b * 2 * E_ + e];
    int v = ei[(size_t)b * 2 * E_ + E_ + e];
    int bucket = ((b << 11) + u) * 8 + (v >> 8);
    int slot = atomicAdd(&cnt[bucket], 1);
    if (slot < ECAP) pck[(size_t)bucket * ECAP + slot] = ((unsigned int)e << 11) | (unsigned int)v;
  } else {
    int k = bb - 1024;                        // 0..255
    for (int c = tid; c < 768; c += 256)
      wT[(size_t)c * 256 + k] = f2b(w[(size_t)k * 768 + c]);
  }
}

// ---------------- QKV projection; Q pre-scaled by log2e/sqrt(DH) ----------------
__global__ __launch_bounds__(256) void qkv_kernel(
    const float* __restrict__ x, const unsigned short* __restrict__ wT,
    const float* __restrict__ bias,
    unsigned short* __restrict__ Qb, unsigned short* __restrict__ Kb, unsigned short* __restrict__ Vt)
{
  int tid = threadIdx.x;
  int wave = tid >> 6, lane = tid & 63, m = lane & 15, quad = lane >> 4;
  int rowbase = blockIdx.x * 16;
  int colbase = blockIdx.y * 64 + wave * 16;
  floatx4 acc = {0.f, 0.f, 0.f, 0.f};
#pragma unroll
  for (int kb = 0; kb < 8; ++kb){
    bf16x8 af = f8_to_bf(x + (size_t)(rowbase + m) * DIN_ + kb * 32 + quad * 8);
    bf16x8 bf = *(const bf16x8*)(wT + (size_t)(colbase + m) * DIN_ + kb * 32 + quad * 8);
    acc = __builtin_amdgcn_mfma_f32_16x16x32_bf16(af, bf, acc, 0, 0, 0);
  }
  int ccol = colbase + m;
  int which = ccol >> 8, hh = (ccol >> 5) & 7, dh = ccol & 31;
  float bv = bias[ccol];
#pragma unroll
  for (int r = 0; r < 4; ++r){
    int row = rowbase + quad * 4 + r;
    int bidx = row >> 11, n = row & (N_ - 1);
    float val = acc[r] + bv;
    size_t bh = (size_t)(bidx * H_ + hh);
    if (which == 0)      Qb[(bh * N_ + n) * DH_ + dh] = f2b(val * QSCALE);
    else if (which == 1) Kb[(bh * N_ + n) * DH_ + dh] = f2b(val);
    else                 Vt[(bh * DH_ + dh) * N_ + n] = f2b(val);
  }
}

// ---------------- fused flash attention, NO-MAX base-2 softmax, barrier-free K-loop ----------------
// 1 WG = (b, h, 16 q-rows). Each wave owns cols [wave*64, wave*64+64) of the S tile
// end-to-end (QK write, moire, self-loop, edge scatter, A-frag readback) -> same-wave
// LDS ordering guarantees correctness with no __syncthreads in the K-loop.
// ONE barrier after the K-loop before reusing S as O-reduction scratch (without it,
// a finished wave's O-partials alias a lagging wave's score slice -> exp2(1e7)=inf -> NaN).
__global__ __launch_bounds__(256) void attn_kernel(
    const unsigned short* __restrict__ Qb, const unsigned short* __restrict__ Kb,
    const unsigned short* __restrict__ Vt, const float* __restrict__ adj,
    const float* __restrict__ ea, const int* __restrict__ cnt, const unsigned int* __restrict__ pck,
    const float* __restrict__ shifts, const float* __restrict__ widths,
    const float* __restrict__ selfW, float* __restrict__ out)
{
  __shared__ float S[16][KT + PAD];   // 16.6 KB; reused as O-reduction scratch at end
  __shared__ float lfin[4][16];

  int bid = blockIdx.x;
  int qt = bid & 127, h = (bid >> 7) & 7, b = bid >> 10;
  int qbase = qt * 16;
  int tid = threadIdx.x, wave = tid >> 6, lane = tid & 63, m = lane & 15, quad = lane >> 4;
  float shift_h = shifts[h];
  float w_h = widths[h];
  float ni = -LOG2E / (2.f * w_h * w_h);        // negative, includes log2e
  float selfW_h = selfW[h] * LOG2E;
  size_t krow = (size_t)(b * H_ + h) * N_;
  size_t vrow = (size_t)(b * H_ + h) * DH_;
  bf16x8 qfrag = *(const bf16x8*)(Qb + (krow + qbase + m) * DH_ + quad * 8);

  float lcur = 0.f;                             // wave's sum-exp partial for row m
  floatx4 o0 = {0,0,0,0}, o1 = {0,0,0,0};       // O partials, dh 0..15 / 16..31

  int c0 = wave * 64 + quad * 8;
  int rowbase8 = (b * N_ + qbase) * 8;
  int diagkt = qbase >> 8;
  const float* adjq = adj + ((size_t)b * N_ + qbase) * N_;   // adj rows for this q-tile
  size_t bE8 = (size_t)b * E_ * 8;

  for (int kt = 0; kt < N_ / KT; ++kt){
    int k0 = kt * KT;
    // ---- QK^T MFMA + moire folded in (C-layout, coalesced scalar adj loads) ----
#pragma unroll
    for (int s = 0; s < 4; ++s){
      int colofs = wave * 64 + s * 16;
      bf16x8 kf = *(const bf16x8*)(Kb + (krow + k0 + colofs + m) * DH_ + quad * 8);
      floatx4 acc = {0,0,0,0};
      acc = __builtin_amdgcn_mfma_f32_16x16x32_bf16(qfrag, kf, acc, 0, 0, 0);
#pragma unroll
      for (int r = 0; r < 4; ++r){
        float a = adjq[(size_t)(quad * 4 + r) * N_ + k0 + colofs + m];
        float d = a - shift_h;
        S[quad * 4 + r][colofs + m] = acc[r] + fmaxf(d * d * ni, LOGMIN2);
      }
    }
    // ---- self-loop fixup (diag tile only; each wave touches only its own cols) ----
    if (kt == diagkt && quad == 0){
      int cl = (qbase - k0) + m;       // local col of the diagonal for row m
      if ((cl >> 6) == wave) S[m][cl] += selfW_h;
    }
    // ---- edge scatter: all buckets of the tile, filtered to this wave's col range ----
#pragma unroll
    for (int it = 0; it < 8; ++it){
      int i = lane + it * 64;
      int r = i >> 5, slot = i & 31;
      int bucket = rowbase8 + r * 8 + kt;
      int nb = cnt[bucket]; nb = nb > ECAP ? ECAP : nb;
      if (slot < nb){
        unsigned int p = pck[(size_t)bucket * ECAP + slot];
        int rel = (int)(p & (N_ - 1)) - k0 - wave * 64;
        if ((unsigned)rel < 64u){
          int e = (int)(p >> 11);
          S[r][wave * 64 + rel] += ea[bE8 + (size_t)e * 8 + h];
        }
      }
    }
    // ---- A-frag readback (own region), p = exp2(s), trunc-pack, PV MFMA ----
    bf16x8 vf0 = *(const bf16x8*)(Vt + (vrow + m) * N_      + k0 + c0);
    bf16x8 vf1 = *(const bf16x8*)(Vt + (vrow + 16 + m) * N_ + k0 + c0);
    bf16x8 vf2 = *(const bf16x8*)(Vt + (vrow + m) * N_      + k0 + c0 + 32);
    bf16x8 vf3 = *(const bf16x8*)(Vt + (vrow + 16 + m) * N_ + k0 + c0 + 32);
    const float* sp = &S[m][c0];
    float4 s0 = *(const float4*)(sp),      s1 = *(const float4*)(sp + 4);
    float4 s2 = *(const float4*)(sp + 32), s3 = *(const float4*)(sp + 36);
    float ps = 0.f, p0, p1;
    union { bf16x8 v; unsigned int u[4]; } pf;
    p0 = exp2f(s0.x); p1 = exp2f(s0.y); ps += ftrunc16(p0) + ftrunc16(p1); pf.u[0] = pack_trunc(p0, p1);
    p0 = exp2f(s0.z); p1 = exp2f(s0.w); ps += ftrunc16(p0) + ftrunc16(p1); pf.u[1] = pack_trunc(p0, p1);
    p0 = exp2f(s1.x); p1 = exp2f(s1.y); ps += ftrunc16(p0) + ftrunc16(p1); pf.u[2] = pack_trunc(p0, p1);
    p0 = exp2f(s1.z); p1 = exp2f(s1.w); ps += ftrunc16(p0) + ftrunc16(p1); pf.u[3] = pack_trunc(p0, p1);
    o0 = __builtin_amdgcn_mfma_f32_16x16x32_bf16(pf.v, vf0, o0, 0, 0, 0);
    o1 = __builtin_amdgcn_mfma_f32_16x16x32_bf16(pf.v, vf1, o1, 0, 0, 0);
    p0 = exp2f(s2.x); p1 = exp2f(s2.y); ps += ftrunc16(p0) + ftrunc16(p1); pf.u[0] = pack_trunc(p0, p1);
    p0 = exp2f(s2.z); p1 = exp2f(s2.w); ps += ftrunc16(p0) + ftrunc16(p1); pf.u[1] = pack_trunc(p0, p1);
    p0 = exp2f(s3.x); p1 = exp2f(s3.y); ps += ftrunc16(p0) + ftrunc16(p1); pf.u[2] = pack_trunc(p0, p1);
    p0 = exp2f(s3.z); p1 = exp2f(s3.w); ps += ftrunc16(p0) + ftrunc16(p1); pf.u[3] = pack_trunc(p0, p1);
    o0 = __builtin_amdgcn_mfma_f32_16x16x32_bf16(pf.v, vf2, o0, 0, 0, 0);
    o1 = __builtin_amdgcn_mfma_f32_16x16x32_bf16(pf.v, vf3, o1, 0, 0, 0);
    ps += __shfl_xor(ps, 16);
    ps += __shfl_xor(ps, 32);
    lcur += ps;
  }

  // ---- REQUIRED barrier: all waves must finish reading S before it becomes scratch ----
  __syncthreads();

  // ---- cross-wave O + l reduction, output fp32 ----
  float* Op = &S[0][0];     // [wave*16 + row][32] flat (8 KB < S)
#pragma unroll
  for (int r = 0; r < 4; ++r){
    Op[(wave * 16 + quad * 4 + r) * 32 + m]      = o0[r];
    Op[(wave * 16 + quad * 4 + r) * 32 + 16 + m] = o1[r];
  }
  if (lane < 16) lfin[wave][m] = lcur;
  __syncthreads();
#pragma unroll
  for (int ii = 0; ii < 2; ++ii){
    int i = tid + ii * 256;
    int r = i >> 5, d = i & 31;
    float o = Op[r * 32 + d] + Op[(16 + r) * 32 + d] + Op[(32 + r) * 32 + d] + Op[(48 + r) * 32 + d];
    float l = lfin[0][r] + lfin[1][r] + lfin[2][r] + lfin[3][r];
    out[((size_t)b * N_ + qbase + r) * (H_ * DH_) + h * DH_ + d] = o / l;
  }
}

extern "C" void kernel_launch(void* const* d_in, const int* in_sizes, int n_in,
                              void* d_out, int out_size, void* d_ws, size_t ws_size,
                              hipStream_t stream)
{
  const float* x      = (const float*)d_in[0];
  const float* adj    = (const float*)d_in[1];
  const float* eattr  = (const float*)d_in[2];
  const float* qkvw   = (const float*)d_in[3];
  const float* qkvb   = (const float*)d_in[4];
  const float* ew1    = (const float*)d_in[5];
  const float* eb1    = (const float*)d_in[6];
  const float* ew2    = (const float*)d_in[7];
  const float* eb2    = (const float*)d_in[8];
  const float* shifts = (const float*)d_in[9];
  const float* widths = (const float*)d_in[10];
  const float* selfW  = (const float*)d_in[11];
  const int*   ei     = (const int*)d_in[12];
  float* out = (float*)d_out;

  char* ws = (char*)d_ws;
  unsigned short* Qb  = (unsigned short*)(ws);                        // 2 MB
  unsigned short* Kb  = (unsigned short*)(ws + ((size_t)2 << 20));    // 2 MB
  unsigned short* Vt  = (unsigned short*)(ws + ((size_t)4 << 20));    // 2 MB
  unsigned short* wT  = (unsigned short*)(ws + ((size_t)6 << 20));    // 384 KB
  float*          ea  = (float*)(ws + ((size_t)7 << 20));             // 4 MB
  int*            cnt = (int*)(ws + ((size_t)11 << 20));              // 128 KB
  unsigned int*  pck  = (unsigned int*)(ws + ((size_t)12 << 20));     // 4 MB (total 16 MB)

  hipMemsetAsync(cnt, 0, (size_t)B_ * N_ * 8 * sizeof(int), stream);
  hipLaunchKernelGGL(prep_kernel, dim3(1280), dim3(256), 0, stream,
                     eattr, ew1, eb1, ew2, eb2, ea, ei, cnt, pck, qkvw, wT);
  hipLaunchKernelGGL(qkv_kernel, dim3(256, 12), dim3(256), 0, stream, x, wT, qkvb, Qb, Kb, Vt);
  hipLaunchKernelGGL(attn_kernel, dim3(B_ * H_ * (N_ / 16)), dim3(256), 0, stream,
                     Qb, Kb, Vt, adj, ea, cnt, pck, shifts, widths, selfW, out);
}